// Round 6
// baseline (145.920 us; speedup 1.0000x reference)
//
#include <hip/hip_runtime.h>

constexpr int BN = 262144;
constexpr int H_ = 100;
constexpr int HHALF = 50;

__device__ __forceinline__ float softplus_f(float x) {
    // |preact| <= ~6 for this data; direct form is safe for x < 88
    return __logf(1.0f + __expf(x));
}

__global__ __launch_bounds__(256) void sde_fused(
    const float* __restrict__ zt1, const float* __restrict__ zt2,
    const float* __restrict__ dtp,
    const float* __restrict__ W1m, const float* __restrict__ b1m,
    const float* __restrict__ W2m, const float* __restrict__ b2m,
    const float* __restrict__ W1d, const float* __restrict__ b1d,
    const float* __restrict__ W2d, const float* __restrict__ b2d,
    float* __restrict__ out)
{
    const int tid  = threadIdx.x;
    const int lane = tid & 63;
    const int wv   = tid >> 6;                  // 0..3
    const int pair = wv >> 1;                   // 0..1
    // half index MUST be wave-uniform in an SGPR so weight loads stay s_load
    const int h    = __builtin_amdgcn_readfirstlane(wv & 1);
    const int row  = blockIdx.x * 128 + pair * 64 + lane;

    const float dt0  = dtp[0];
    const float sqdt = sqrtf(dt0);

    // zt1 row (2x float4, coalesced)
    float x[8];
    {
        const float4* p = reinterpret_cast<const float4*>(zt1) + (size_t)row * 2;
        float4 a = p[0], b = p[1];
        x[0]=a.x; x[1]=a.y; x[2]=a.z; x[3]=a.w;
        x[4]=b.x; x[5]=b.y; x[6]=b.z; x[7]=b.w;
    }

    float am[8], ad[8];
    if (h == 0) {
        #pragma unroll
        for (int k = 0; k < 8; ++k) { am[k] = b2m[k]; ad[k] = b2d[k]; }
    } else {
        #pragma unroll
        for (int k = 0; k < 8; ++k) { am[k] = 0.f; ad[k] = 0.f; }
    }

    // each wave handles 50 of the 100 hidden units; weights are wave-uniform -> s_load
    const int j0 = h * HHALF;
    #pragma unroll 2
    for (int jj = 0; jj < HHALF; ++jj) {
        const int j = j0 + jj;
        float pm = b1m[j], pd = b1d[j];
        #pragma unroll
        for (int k = 0; k < 8; ++k) {
            pm = fmaf(x[k], W1m[j*8 + k], pm);
            pd = fmaf(x[k], W1d[j*8 + k], pd);
        }
        const float hm = softplus_f(pm);
        const float hd = softplus_f(pd);
        #pragma unroll
        for (int k = 0; k < 8; ++k) {
            am[k] = fmaf(hm, W2m[k*H_ + j], am[k]);
            ad[k] = fmaf(hd, W2d[k*H_ + j], ad[k]);
        }
    }

    // exchange partials with partner wave (tid ^ 64); 9-stride pad -> 2-way bank alias (free)
    __shared__ float xch[256 * 9];
    float* mine = &xch[tid * 9];
    if (h == 0) {   // I finish k=0..3; ship k=4..7 to partner
        mine[0]=am[4]; mine[1]=am[5]; mine[2]=am[6]; mine[3]=am[7];
        mine[4]=ad[4]; mine[5]=ad[5]; mine[6]=ad[6]; mine[7]=ad[7];
    } else {        // I finish k=4..7; ship k=0..3
        mine[0]=am[0]; mine[1]=am[1]; mine[2]=am[2]; mine[3]=am[3];
        mine[4]=ad[0]; mine[5]=ad[1]; mine[6]=ad[2]; mine[7]=ad[3];
    }
    __syncthreads();
    const float* part = &xch[(tid ^ 64) * 9];

    float* __restrict__ mu_out = out + 1;
    float* __restrict__ sg_out = out + 1 + (size_t)BN * 8;

    float t1 = 0.f, t2 = 0.f, t3 = 0.f, t4 = 0.f;

    // epilogue for my 4 output columns; all register indices static (no scratch)
#define EPI(K0)                                                              \
    {                                                                        \
        const float4 zb = *(reinterpret_cast<const float4*>(zt2) +           \
                            ((size_t)row * 2 + (K0 / 4)));                   \
        const float z2v[4] = {zb.x, zb.y, zb.z, zb.w};                       \
        _Pragma("unroll")                                                    \
        for (int q = 0; q < 4; ++q) {                                        \
            const int k = K0 + q;                                            \
            const float a_m = am[k] + part[q];                               \
            const float a_d = ad[k] + part[4 + q];                           \
            const float mu = a_m * dt0;                                      \
            const float y  = a_d;              /* log(D) exactly */          \
            const float Dk = __expf(y);                                      \
            const float iv = __expf(-2.0f * y); /* 1/D^2 */                  \
            const float dz = z2v[q] - x[k];                                  \
            t1 += y;                                                         \
            t2 = fmaf(dz * dz, iv, t2);                                      \
            t3 = fmaf(dz * mu, iv, t3);                                      \
            t4 = fmaf(mu * mu, iv, t4);                                      \
            mu_out[(size_t)row * 8 + k] = mu;                                \
            sg_out[(size_t)row * 8 + k] = Dk * sqdt;                         \
        }                                                                    \
    }

    if (h == 0) { EPI(0) } else { EPI(4) }
#undef EPI

    // per-thread share: 0.5*const + 0.5*(2 t1 + t2 - 2 t3 + t4) over my 4 k's
    float nll = fmaf(0.5f, (2.0f * t1 + t2 - 2.0f * t3 + t4),
                     3.67575413281869039f); // 0.5 * (DIM/2 * log(2*pi))

    #pragma unroll
    for (int off = 32; off > 0; off >>= 1) nll += __shfl_down(nll, off);

    __shared__ float wsum[4];
    if (lane == 0) wsum[wv] = nll;
    __syncthreads();
    if (tid == 0) atomicAdd(out, wsum[0] + wsum[1] + wsum[2] + wsum[3]);
}

extern "C" void kernel_launch(void* const* d_in, const int* in_sizes, int n_in,
                              void* d_out, int out_size, void* d_ws, size_t ws_size,
                              hipStream_t stream) {
    hipMemsetAsync(d_out, 0, sizeof(float), stream);
    sde_fused<<<BN / 128, 256, 0, stream>>>(
        (const float*)d_in[0], (const float*)d_in[1], (const float*)d_in[2],
        (const float*)d_in[3], (const float*)d_in[4],
        (const float*)d_in[5], (const float*)d_in[6],
        (const float*)d_in[7], (const float*)d_in[8],
        (const float*)d_in[9], (const float*)d_in[10],
        (float*)d_out);
}

// Round 11
// 136.981 us; speedup vs baseline: 1.0653x; 1.0653x over previous
//
#include <hip/hip_runtime.h>

constexpr int BN = 262144;
constexpr int H_ = 100;
constexpr int HHALF = 50;
constexpr int RS = 36; // packed weight-row stride in floats (144 B, 16B-aligned)

__device__ __forceinline__ float softplus_f(float x) {
    // |preact| <= ~6 for this data; direct form is safe for x < 88
    return __logf(1.0f + __expf(x));
}

__global__ __launch_bounds__(256) void sde_fused(
    const float* __restrict__ zt1, const float* __restrict__ zt2,
    const float* __restrict__ dtp,
    const float* __restrict__ W1m, const float* __restrict__ b1m,
    const float* __restrict__ W2m, const float* __restrict__ b2m,
    const float* __restrict__ W1d, const float* __restrict__ b1d,
    const float* __restrict__ W2d, const float* __restrict__ b2d,
    float* __restrict__ out)
{
    // one LDS slab, time-shared (barrier-separated): weight rows during the
    // K-loop, then the partner-exchange buffer (needs 256*9=2304 <= 3600 floats)
    __shared__ __align__(16) float smem[H_ * RS];   // 14400 B
    __shared__ float wsum[4];

    const int tid  = threadIdx.x;
    const int lane = tid & 63;
    const int wv   = tid >> 6;                  // 0..3
    const int pair = wv >> 1;                   // 0..1
    // half index MUST be wave-uniform in an SGPR
    const int h    = __builtin_amdgcn_readfirstlane(wv & 1);
    const int row  = blockIdx.x * 128 + pair * 64 + lane;

    // ---- stage packed weight rows:
    // smem[j*36 + {0..7:W1m[j], 8..15:W1d[j], 16..23:W2m[.][j], 24..31:W2d[.][j], 32:b1m[j], 33:b1d[j]}]
    for (int idx = tid; idx < 800; idx += 256) {
        const int j = idx >> 3, k = idx & 7;         // W1* is [100][8] row-major
        smem[j * RS + 0 + k] = W1m[idx];
        smem[j * RS + 8 + k] = W1d[idx];
    }
    for (int idx = tid; idx < 800; idx += 256) {
        const int k = idx / 100, j = idx - k * 100;  // W2* is [8][100] row-major -> transpose
        smem[j * RS + 16 + k] = W2m[idx];
        smem[j * RS + 24 + k] = W2d[idx];
    }
    if (tid < H_) {
        smem[tid * RS + 32] = b1m[tid];
        smem[tid * RS + 33] = b1d[tid];
    }

    const float dt0  = dtp[0];
    const float sqdt = sqrtf(dt0);

    // zt1 row (2x float4, coalesced)
    float x[8];
    {
        const float4* p = reinterpret_cast<const float4*>(zt1) + (size_t)row * 2;
        float4 a = p[0], b = p[1];
        x[0]=a.x; x[1]=a.y; x[2]=a.z; x[3]=a.w;
        x[4]=b.x; x[5]=b.y; x[6]=b.z; x[7]=b.w;
    }
    // prefetch zt2 now; consumed only after the K-loop (latency buried under compute)
    float4 z2a, z2b;
    {
        const float4* p = reinterpret_cast<const float4*>(zt2) + (size_t)row * 2;
        z2a = p[0]; z2b = p[1];
    }

    float am[8], ad[8];
    if (h == 0) {
        #pragma unroll
        for (int k = 0; k < 8; ++k) { am[k] = b2m[k]; ad[k] = b2d[k]; }
    } else {
        #pragma unroll
        for (int k = 0; k < 8; ++k) { am[k] = 0.f; ad[k] = 0.f; }
    }

    __syncthreads();   // staging complete

    // each wave handles 50 of the 100 hidden units; all loop operands come from
    // LDS broadcast reads (uniform address) -> zero scalar loads in the loop
    const float* __restrict__ base = smem + h * (HHALF * RS);
    #pragma unroll 2
    for (int jj = 0; jj < HHALF; ++jj) {
        const float* r = base + jj * RS;
        const float4 w1m0 = *(const float4*)(r + 0);
        const float4 w1m1 = *(const float4*)(r + 4);
        const float4 w1d0 = *(const float4*)(r + 8);
        const float4 w1d1 = *(const float4*)(r + 12);
        const float2 bb   = *(const float2*)(r + 32);
        float pm = bb.x, pd = bb.y;
        pm = fmaf(x[0], w1m0.x, pm); pm = fmaf(x[1], w1m0.y, pm);
        pm = fmaf(x[2], w1m0.z, pm); pm = fmaf(x[3], w1m0.w, pm);
        pm = fmaf(x[4], w1m1.x, pm); pm = fmaf(x[5], w1m1.y, pm);
        pm = fmaf(x[6], w1m1.z, pm); pm = fmaf(x[7], w1m1.w, pm);
        pd = fmaf(x[0], w1d0.x, pd); pd = fmaf(x[1], w1d0.y, pd);
        pd = fmaf(x[2], w1d0.z, pd); pd = fmaf(x[3], w1d0.w, pd);
        pd = fmaf(x[4], w1d1.x, pd); pd = fmaf(x[5], w1d1.y, pd);
        pd = fmaf(x[6], w1d1.z, pd); pd = fmaf(x[7], w1d1.w, pd);
        const float hm = softplus_f(pm);
        const float hd = softplus_f(pd);
        const float4 w2m0 = *(const float4*)(r + 16);
        const float4 w2m1 = *(const float4*)(r + 20);
        const float4 w2d0 = *(const float4*)(r + 24);
        const float4 w2d1 = *(const float4*)(r + 28);
        am[0] = fmaf(hm, w2m0.x, am[0]); am[1] = fmaf(hm, w2m0.y, am[1]);
        am[2] = fmaf(hm, w2m0.z, am[2]); am[3] = fmaf(hm, w2m0.w, am[3]);
        am[4] = fmaf(hm, w2m1.x, am[4]); am[5] = fmaf(hm, w2m1.y, am[5]);
        am[6] = fmaf(hm, w2m1.z, am[6]); am[7] = fmaf(hm, w2m1.w, am[7]);
        ad[0] = fmaf(hd, w2d0.x, ad[0]); ad[1] = fmaf(hd, w2d0.y, ad[1]);
        ad[2] = fmaf(hd, w2d0.z, ad[2]); ad[3] = fmaf(hd, w2d0.w, ad[3]);
        ad[4] = fmaf(hd, w2d1.x, ad[4]); ad[5] = fmaf(hd, w2d1.y, ad[5]);
        ad[6] = fmaf(hd, w2d1.z, ad[6]); ad[7] = fmaf(hd, w2d1.w, ad[7]);
    }

    __syncthreads();   // all waves done reading weight rows; smem reused for exchange

    // exchange partials with partner wave (tid ^ 64); stride 9 -> 2-way bank alias (free)
    float* mine = smem + tid * 9;
    if (h == 0) {   // I finish k=0..3; ship k=4..7 to partner
        mine[0]=am[4]; mine[1]=am[5]; mine[2]=am[6]; mine[3]=am[7];
        mine[4]=ad[4]; mine[5]=ad[5]; mine[6]=ad[6]; mine[7]=ad[7];
    } else {        // I finish k=4..7; ship k=0..3
        mine[0]=am[0]; mine[1]=am[1]; mine[2]=am[2]; mine[3]=am[3];
        mine[4]=ad[0]; mine[5]=ad[1]; mine[6]=ad[2]; mine[7]=ad[3];
    }
    __syncthreads();
    const float* part = smem + (tid ^ 64) * 9;

    float* __restrict__ mu_out = out + 1;
    float* __restrict__ sg_out = out + 1 + (size_t)BN * 8;

    float t1 = 0.f, t2 = 0.f, t3 = 0.f, t4 = 0.f;

    // epilogue for my 4 output columns; all register indices static (no scratch)
#define EPI(K0, ZB)                                                          \
    {                                                                        \
        const float z2v[4] = {ZB.x, ZB.y, ZB.z, ZB.w};                       \
        _Pragma("unroll")                                                    \
        for (int q = 0; q < 4; ++q) {                                        \
            const int k = K0 + q;                                            \
            const float a_m = am[k] + part[q];                               \
            const float a_d = ad[k] + part[4 + q];                           \
            const float mu = a_m * dt0;                                      \
            const float y  = a_d;              /* log(D) exactly */          \
            const float Dk = __expf(y);                                      \
            const float iv = __expf(-2.0f * y); /* 1/D^2 */                  \
            const float dz = z2v[q] - x[k];                                  \
            t1 += y;                                                         \
            t2 = fmaf(dz * dz, iv, t2);                                      \
            t3 = fmaf(dz * mu, iv, t3);                                      \
            t4 = fmaf(mu * mu, iv, t4);                                      \
            mu_out[(size_t)row * 8 + k] = mu;                                \
            sg_out[(size_t)row * 8 + k] = Dk * sqdt;                         \
        }                                                                    \
    }

    if (h == 0) { EPI(0, z2a) } else { EPI(4, z2b) }
#undef EPI

    // per-thread share: 0.5*const + 0.5*(2 t1 + t2 - 2 t3 + t4) over my 4 k's
    float nll = fmaf(0.5f, (2.0f * t1 + t2 - 2.0f * t3 + t4),
                     3.67575413281869039f); // 0.5 * (DIM/2 * log(2*pi))

    #pragma unroll
    for (int off = 32; off > 0; off >>= 1) nll += __shfl_down(nll, off);

    __syncthreads();   // protect wsum reuse ordering across the shfl path
    if (lane == 0) wsum[wv] = nll;
    __syncthreads();
    if (tid == 0) atomicAdd(out, wsum[0] + wsum[1] + wsum[2] + wsum[3]);
}

extern "C" void kernel_launch(void* const* d_in, const int* in_sizes, int n_in,
                              void* d_out, int out_size, void* d_ws, size_t ws_size,
                              hipStream_t stream) {
    hipMemsetAsync(d_out, 0, sizeof(float), stream);
    sde_fused<<<BN / 128, 256, 0, stream>>>(
        (const float*)d_in[0], (const float*)d_in[1], (const float*)d_in[2],
        (const float*)d_in[3], (const float*)d_in[4],
        (const float*)d_in[5], (const float*)d_in[6],
        (const float*)d_in[7], (const float*)d_in[8],
        (const float*)d_in[9], (const float*)d_in[10],
        (float*)d_out);
}